// Round 3
// baseline (9754.333 us; speedup 1.0000x reference)
//
#include <hip/hip_runtime.h>

// ---------------------------------------------------------------------------
// SequencePredictorRNN: LSTM(1024 steps, batch 128, d=1024) + 512-class readout
//
// Persistent kernel, 128 blocks x 512 threads. Block b owns hidden units
// [8b,8b+8) -> 32 packed gate columns; XG input-gate table (512 classes) in LDS.
// Logits MFMA hidden under the barrier wait (3-deep h ring).
//
// R3: register-resident W_hh fragments (kill the per-step LDS read stream).
//  Prev: each wave re-read its 64 h8v Ws fragments from LDS EVERY step ->
//  512 ds_read_b128/block/step ~ 2.6us of LDS pipe time (the dominant busy
//  term; SQ_LDS_BANK_CONFLICT 3.1e8 constant across rounds).
//  Now: waves re-roled as (4 row-groups x 32 rows) x (2 K-halves of 512).
//  Per wave W = 32 h8v = 128 VGPRs, loaded ONCE before the loop. Gates become
//  MFMA + global h loads only; a 16KB LDS partial-sum exchange (kh0 writes,
//  kh1 adds + cell update) replaces the Ws reads. Freed Ws LDS region is the
//  reduction buffer. Poll wave chosen != logits waves so detect isn't
//  serialized behind the spin-hidden logits MFMA.
//  Sync structure unchanged from R2 (write-through h, relaxed RMW, relaxed
//  polls + one acquire fence).
// Workspace: 1KB counters + 3 x 128x1024 fp16 h buffers = 769 KB.
// ---------------------------------------------------------------------------

typedef _Float16 h8v  __attribute__((ext_vector_type(8)));   // 8 x fp16 (4 VGPR)
typedef float    f32x4 __attribute__((ext_vector_type(4)));

#define SEQL  1024
#define BATCH 128
#define DM    1024
#define NC    512
#define PAD   1032
#define HELEMS (BATCH * DM)    // fp16 elems per h buffer (256 KB)

__device__ __forceinline__ float sigm(float x)   { return 1.0f / (1.0f + __expf(-x)); }
__device__ __forceinline__ float tanh_f(float x) { return 1.0f - 2.0f / (__expf(2.0f * x) + 1.0f); }

__device__ __forceinline__ h8v ld8f_cvt(const float* p) {
    const float4 a = ((const float4*)p)[0];
    const float4 b = ((const float4*)p)[1];
    h8v v;
    v[0] = (_Float16)a.x; v[1] = (_Float16)a.y;
    v[2] = (_Float16)a.z; v[3] = (_Float16)a.w;
    v[4] = (_Float16)b.x; v[5] = (_Float16)b.y;
    v[6] = (_Float16)b.z; v[7] = (_Float16)b.w;
    return v;
}

// agent-scope write-through fp16 store (global_store_short sc1, compiler-tracked)
__device__ __forceinline__ void st_h_agent(_Float16* p, float v) {
    _Float16 hv = (_Float16)v;
    unsigned short u = __builtin_bit_cast(unsigned short, hv);
    __hip_atomic_store((unsigned short*)p, u, __ATOMIC_RELAXED,
                       __HIP_MEMORY_SCOPE_AGENT);
}

__global__ __launch_bounds__(512) void lstm_all_kernel(
    const int*   __restrict__ x,     const float* __restrict__ emb,
    const float* __restrict__ Wih,   const float* __restrict__ Whh,
    const float* __restrict__ bih,   const float* __restrict__ bhh,
    const float* __restrict__ Wpred, const float* __restrict__ bpred,
    _Float16* __restrict__ hbuf, unsigned* __restrict__ cnt,
    float* __restrict__ out)
{
    __shared__ __align__(16) _Float16 Ws[32 * PAD];  // staging; reused as fRed
    __shared__ __align__(16) _Float16 Wp[16 * PAD];  // W_pred slice (16 x 1024)
    __shared__ _Float16 XGs[512 * 32];               // XG table: class x 32 cols
    __shared__ float biasS[32];
    float* const fRed = (float*)Ws;                  // 16KB reduction buffer

    const int tid  = threadIdx.x;
    const int b    = blockIdx.x;
    const int u0   = b * 8;                 // first hidden unit owned
    const int C0   = (b & 31) * 16;         // logits column base
    const int wave = tid >> 6, lane = tid & 63;
    const int q = lane >> 4, p15 = lane & 15;
    const int kh = wave >> 2;               // K half: k in [kh*512, kh*512+512)
    const int rg = wave & 3;                // row group: rows [32rg, 32rg+32)

    // ---- Phase A: stage W_ih slice, W_pred slice, biases ----
    for (int idx = tid; idx < 32 * 128; idx += 512) {
        int c = idx >> 7, kc = idx & 127;
        int g = c >> 3, j = c & 7;
        *(h8v*)&Ws[c * PAD + kc * 8] =
            ld8f_cvt(&Wih[(g * 1024 + u0 + j) * DM + kc * 8]);
    }
    for (int idx = tid; idx < 16 * 128; idx += 512) {
        int rr = idx >> 7, kc = idx & 127;
        *(h8v*)&Wp[rr * PAD + kc * 8] =
            ld8f_cvt(&Wpred[(C0 + rr) * DM + kc * 8]);
    }
    if (tid < 32) {
        int g = tid >> 3, j = tid & 7;
        int r = g * 1024 + u0 + j;
        biasS[tid] = bih[r] + bhh[r];
    }
    __syncthreads();

    const _Float16* wsp0 = &Ws[p15 * PAD + q * 8];          // packed cols 0..15
    const _Float16* wsp1 = &Ws[(16 + p15) * PAD + q * 8];   // packed cols 16..31
    const _Float16* wpp  = &Wp[p15 * PAD + q * 8];

    // ---- Phase B: XG table. Each wave: 64 classes (4 m-tiles of 16) ----
#pragma unroll
    for (int mt = 0; mt < 4; ++mt) {
        f32x4 a0 = {0.f,0.f,0.f,0.f}, a1 = {0.f,0.f,0.f,0.f};
        const float* ep = emb + (wave * 64 + mt * 16 + p15) * DM + q * 8;
#pragma unroll 8
        for (int ks = 0; ks < 32; ++ks) {
            h8v av = ld8f_cvt(ep + ks * 32);
            a0 = __builtin_amdgcn_mfma_f32_16x16x32_f16(
                av, *(const h8v*)(wsp0 + ks * 32), a0, 0, 0, 0);
            a1 = __builtin_amdgcn_mfma_f32_16x16x32_f16(
                av, *(const h8v*)(wsp1 + ks * 32), a1, 0, 0, 0);
        }
#pragma unroll
        for (int reg = 0; reg < 4; ++reg) {
            int row = wave * 64 + mt * 16 + q * 4 + reg;    // class index
            XGs[row * 32 + p15]      = (_Float16)(a0[reg] + biasS[p15]);
            XGs[row * 32 + 16 + p15] = (_Float16)(a1[reg] + biasS[16 + p15]);
        }
    }
    __syncthreads();

    // ---- Phase C: restage Ws with W_hh slice ----
    for (int idx = tid; idx < 32 * 128; idx += 512) {
        int c = idx >> 7, kc = idx & 127;
        int g = c >> 3, j = c & 7;
        *(h8v*)&Ws[c * PAD + kc * 8] =
            ld8f_cvt(&Whh[(g * 1024 + u0 + j) * DM + kc * 8]);
    }
    __syncthreads();

    // ---- extract this lane's W_hh fragments into registers (loop-invariant):
    // wave (kh,rg) needs k = kh*512 + ks*32 + q*8, cols p15 / 16+p15.
    h8v wf0[16], wf1[16];
#pragma unroll
    for (int ks = 0; ks < 16; ++ks) {
        int kc = kh * 64 + ks * 4 + q;
        wf0[ks] = *(const h8v*)&Ws[p15 * PAD + kc * 8];
        wf1[ks] = *(const h8v*)&Ws[(16 + p15) * PAD + kc * 8];
    }
    __syncthreads();   // everyone done with Ws before fRed reuse

    const int wA = (b >> 5) * 2;                       // logits waves
    const bool isLog = (wave == wA) || (wave == wA + 1);
    const int  pw    = (wA + 2) & 7;                   // poll wave (never logits)
    const float bp_l = isLog ? bpred[C0 + p15] : 0.f;

    float csr[2][4] = {{0.f,0.f,0.f,0.f},{0.f,0.f,0.f,0.f}};  // cell state

    // logits reader base into tiled h (rows wave*16..+16, k offset q*8)
    const int hlane = q * 1024 + (wave * 16 + p15) * 8;
    // per-lane slot in the reduction buffer (64B aligned)
    float* const frp = fRed + (rg * 64 + lane) * 16;

    // prefetched XG gate values for step 0 (kh0 waves carry the XG init)
    f32x4 pA[2], pB[2];
    if (kh == 0) {
#pragma unroll
        for (int mt = 0; mt < 2; ++mt)
#pragma unroll
        for (int reg = 0; reg < 4; ++reg) {
            int row = rg * 32 + mt * 16 + q * 4 + reg;
            int cls = x[row];
            pA[mt][reg] = (float)XGs[cls * 32 + p15];
            pB[mt][reg] = (float)XGs[cls * 32 + 16 + p15];
        }
    }

#pragma unroll 1
    for (int p = 0; p <= SEQL; ++p) {
        const _Float16* hprevT = hbuf + (p % 3) * HELEMS;
        _Float16*       hnewT  = hbuf + ((p + 1) % 3) * HELEMS;
        const bool doGates = (p < SEQL);
        const bool doLogW  = (p >= 1) && isLog;

        if (doGates) {
            f32x4 acc[2][2];
            if (kh == 0) {
                acc[0][0] = pA[0]; acc[0][1] = pB[0];
                acc[1][0] = pA[1]; acc[1][1] = pB[1];
            } else {
                f32x4 z = {0.f,0.f,0.f,0.f};
                acc[0][0] = z; acc[0][1] = z; acc[1][0] = z; acc[1][1] = z;
            }
            // h rows 32rg+p15 (+16 for mt1), k-chunks kh*64 + ks*4 + q
            const _Float16* hb =
                hprevT + (kh * 64 + q) * 1024 + (rg * 32 + p15) * 8;
#pragma unroll
            for (int ks = 0; ks < 16; ++ks) {
                h8v a0 = *(const h8v*)(hb + ks * 4096);
                h8v a1 = *(const h8v*)(hb + ks * 4096 + 128);
                acc[0][0] = __builtin_amdgcn_mfma_f32_16x16x32_f16(
                    a0, wf0[ks], acc[0][0], 0, 0, 0);
                acc[0][1] = __builtin_amdgcn_mfma_f32_16x16x32_f16(
                    a0, wf1[ks], acc[0][1], 0, 0, 0);
                acc[1][0] = __builtin_amdgcn_mfma_f32_16x16x32_f16(
                    a1, wf0[ks], acc[1][0], 0, 0, 0);
                acc[1][1] = __builtin_amdgcn_mfma_f32_16x16x32_f16(
                    a1, wf1[ks], acc[1][1], 0, 0, 0);
            }
            if (kh == 0) {                 // publish partials (16KB total)
                *(f32x4*)(frp)      = acc[0][0];
                *(f32x4*)(frp + 4)  = acc[0][1];
                *(f32x4*)(frp + 8)  = acc[1][0];
                *(f32x4*)(frp + 12) = acc[1][1];
            }
            __syncthreads();               // partials visible to kh1 partner
            if (kh == 1) {
                acc[0][0] += *(const f32x4*)(frp);
                acc[0][1] += *(const f32x4*)(frp + 4);
                acc[1][0] += *(const f32x4*)(frp + 8);
                acc[1][1] += *(const f32x4*)(frp + 12);
                // cell update: lane p15<8 owns unit j=p15; lanes p15+8 hold f,o
#pragma unroll
                for (int mt = 0; mt < 2; ++mt)
#pragma unroll
                for (int reg = 0; reg < 4; ++reg) {
                    float fv = __shfl_xor(acc[mt][0][reg], 8, 64);
                    float ov = __shfl_xor(acc[mt][1][reg], 8, 64);
                    if (p15 < 8) {
                        float iv = sigm(acc[mt][0][reg]);
                        float ff = sigm(fv);
                        float gv = tanh_f(acc[mt][1][reg]);
                        float oo = sigm(ov);
                        float c  = ff * csr[mt][reg] + iv * gv;
                        csr[mt][reg] = c;
                        int row = rg * 32 + mt * 16 + q * 4 + reg;
                        st_h_agent(&hnewT[b * 1024 + row * 8 + p15],
                                   oo * tanh_f(c));
                    }
                }
            }
            __syncthreads();               // drains kh1 sc1 stores to LLC
            if (tid == 0)                  // RELAXED arrival: no buffer_wbl2
                __hip_atomic_fetch_add(&cnt[(b & 7) * 32], 1u,
                                       __ATOMIC_RELAXED, __HIP_MEMORY_SCOPE_AGENT);

            // prefetch next step's XG gate values (hides under spin)
            if (kh == 0 && p + 1 < SEQL) {
#pragma unroll
                for (int mt = 0; mt < 2; ++mt)
#pragma unroll
                for (int reg = 0; reg < 4; ++reg) {
                    int row = rg * 32 + mt * 16 + q * 4 + reg;
                    int cls = x[(p + 1) * BATCH + row];
                    pA[mt][reg] = (float)XGs[cls * 32 + p15];
                    pB[mt][reg] = (float)XGs[cls * 32 + 16 + p15];
                }
            }
        }

        // ---- logits for timestep p-1, hidden under the barrier wait ----
        if (doLogW) {
            f32x4 accL = {0.f,0.f,0.f,0.f};
            const _Float16* hb = hprevT + hlane;
#pragma unroll 1
            for (int kc = 0; kc < 4; ++kc) {
                h8v af[8];
#pragma unroll
                for (int jj = 0; jj < 8; ++jj)
                    af[jj] = *(const h8v*)(hb + (kc * 32 + jj * 4) * 1024);
#pragma unroll
                for (int jj = 0; jj < 8; ++jj)
                    accL = __builtin_amdgcn_mfma_f32_16x16x32_f16(
                        af[jj], *(const h8v*)(wpp + (kc * 8 + jj) * 32), accL, 0, 0, 0);
            }
            const int s = p - 1;
#pragma unroll
            for (int reg = 0; reg < 4; ++reg) {
                int row = wave * 16 + q * 4 + reg;      // batch row
                __builtin_nontemporal_store(accL[reg] + bp_l,
                    &out[row * (SEQL * NC) + s * NC + C0 + p15]);
            }
        }

        if (doGates) {
            // ---- barrier exit: relaxed polls; ONE acquire inv per step ----
            if (wave == pw && lane < 8) {
                const unsigned target = (unsigned)(p + 1) * 16u;
                while (__hip_atomic_load(&cnt[lane * 32], __ATOMIC_RELAXED,
                                         __HIP_MEMORY_SCOPE_AGENT) < target)
                    __builtin_amdgcn_s_sleep(1);
                // buffer_inv sc1: drops clean lines only (dirty out survives)
                __builtin_amdgcn_fence(__ATOMIC_ACQUIRE, "agent");
            }
            __syncthreads();
        }
    }
}

// ---------------------------------------------------------------------------
extern "C" void kernel_launch(void* const* d_in, const int* in_sizes, int n_in,
                              void* d_out, int out_size, void* d_ws, size_t ws_size,
                              hipStream_t stream) {
    (void)in_sizes; (void)n_in; (void)out_size; (void)ws_size;
    const int*   x     = (const int*)  d_in[0];
    const float* emb   = (const float*)d_in[1];
    const float* Wih   = (const float*)d_in[2];
    const float* Whh   = (const float*)d_in[3];
    const float* bih   = (const float*)d_in[4];
    const float* bhh   = (const float*)d_in[5];
    const float* Wpred = (const float*)d_in[6];
    const float* bpred = (const float*)d_in[7];
    float* out = (float*)d_out;

    unsigned*  cnt  = (unsigned*)d_ws;                   // 8 counters, 128B apart
    _Float16*  hbuf = (_Float16*)((char*)d_ws + 1024);   // 3 x 128x1024 fp16 ring

    // zero counters + h ring buffer 0 (buffers 1,2 are fully written before read)
    hipMemsetAsync(d_ws, 0, 1024 + HELEMS * 2, stream);

    hipLaunchKernelGGL(lstm_all_kernel, dim3(128), dim3(512), 0, stream,
                       x, emb, Wih, Whh, bih, bhh, Wpred, bpred,
                       hbuf, cnt, out);
}

// Round 4
// 9350.918 us; speedup vs baseline: 1.0431x; 1.0431x over previous
//
#include <hip/hip_runtime.h>

// ---------------------------------------------------------------------------
// SequencePredictorRNN: LSTM(1024 steps, batch 128, d=1024) + 512-class readout
//
// Persistent kernel, 128 blocks x 512 threads. Block b owns hidden units
// [8b,8b+8) -> 32 packed gate columns in LDS; XG input-gate table (512 classes)
// in LDS. Logits MFMA hidden under the barrier wait (3-deep h ring).
//
// R4 = revert to R2 structure (R3's K-split exchange regressed: it added a
// publish->barrier->reduce hop to the per-step latency chain, and VGPR=120
// proved the W fragments never went register-resident) + three chain cuts:
//  * deferred logits stores: accL held in regs across the barrier, NT-stored
//    at the TOP of the next gates phase. Previously the 16 scattered 64B HBM
//    write-acks gated the barrier-EXIT syncthreads (vmcnt(0)) every step —
//    latency + per-block jitter amplified by the 128-block barrier max.
//    Now they drain at the gates sync, hidden under ~2us of compute.
//  * gate accumulators split in k (accA0/A1, accB0/B1): MFMA dependent chain
//    32 -> 16 deep (~-0.15us).
//  * __launch_bounds__(512, 2): grant the full 256-VGPR budget (LDS already
//    forces 1 block/CU = 2 waves/SIMD) so nothing silently spills.
//  * arrival RMW by poll-wave lane0 (wave0 is a logits wave for b<32).
// Sync structure otherwise unchanged from R2: write-through h stores (sc1),
// relaxed arrival RMW, relaxed polls + one acquire fence per step.
// Workspace: 1KB counters + 3 x 128x1024 fp16 h buffers = 769 KB.
// ---------------------------------------------------------------------------

typedef _Float16 h8v  __attribute__((ext_vector_type(8)));   // 8 x fp16 (4 VGPR)
typedef float    f32x4 __attribute__((ext_vector_type(4)));

#define SEQL  1024
#define BATCH 128
#define DM    1024
#define NC    512
#define PAD   1032
#define HELEMS (BATCH * DM)    // fp16 elems per h buffer (256 KB)

__device__ __forceinline__ float sigm(float x)   { return 1.0f / (1.0f + __expf(-x)); }
__device__ __forceinline__ float tanh_f(float x) { return 1.0f - 2.0f / (__expf(2.0f * x) + 1.0f); }

__device__ __forceinline__ h8v ld8f_cvt(const float* p) {
    const float4 a = ((const float4*)p)[0];
    const float4 b = ((const float4*)p)[1];
    h8v v;
    v[0] = (_Float16)a.x; v[1] = (_Float16)a.y;
    v[2] = (_Float16)a.z; v[3] = (_Float16)a.w;
    v[4] = (_Float16)b.x; v[5] = (_Float16)b.y;
    v[6] = (_Float16)b.z; v[7] = (_Float16)b.w;
    return v;
}

// agent-scope write-through fp16 store (global_store_short sc1, compiler-tracked)
__device__ __forceinline__ void st_h_agent(_Float16* p, float v) {
    _Float16 hv = (_Float16)v;
    unsigned short u = __builtin_bit_cast(unsigned short, hv);
    __hip_atomic_store((unsigned short*)p, u, __ATOMIC_RELAXED,
                       __HIP_MEMORY_SCOPE_AGENT);
}

__global__ __launch_bounds__(512, 2) void lstm_all_kernel(
    const int*   __restrict__ x,     const float* __restrict__ emb,
    const float* __restrict__ Wih,   const float* __restrict__ Whh,
    const float* __restrict__ bih,   const float* __restrict__ bhh,
    const float* __restrict__ Wpred, const float* __restrict__ bpred,
    _Float16* __restrict__ hbuf, unsigned* __restrict__ cnt,
    float* __restrict__ out)
{
    __shared__ __align__(16) _Float16 Ws[32 * PAD];  // W_ih slice, then W_hh
    __shared__ __align__(16) _Float16 Wp[16 * PAD];  // W_pred slice (16 x 1024)
    __shared__ _Float16 XGs[512 * 32];               // XG table: class x 32 cols
    __shared__ float biasS[32];

    const int tid  = threadIdx.x;
    const int b    = blockIdx.x;
    const int u0   = b * 8;                 // first hidden unit owned
    const int C0   = (b & 31) * 16;         // logits column base
    const int wave = tid >> 6, lane = tid & 63;
    const int q = lane >> 4, p15 = lane & 15;

    // ---- Phase A: stage W_ih slice, W_pred slice, biases ----
    for (int idx = tid; idx < 32 * 128; idx += 512) {
        int c = idx >> 7, kc = idx & 127;
        int g = c >> 3, j = c & 7;
        *(h8v*)&Ws[c * PAD + kc * 8] =
            ld8f_cvt(&Wih[(g * 1024 + u0 + j) * DM + kc * 8]);
    }
    for (int idx = tid; idx < 16 * 128; idx += 512) {
        int rr = idx >> 7, kc = idx & 127;
        *(h8v*)&Wp[rr * PAD + kc * 8] =
            ld8f_cvt(&Wpred[(C0 + rr) * DM + kc * 8]);
    }
    if (tid < 32) {
        int g = tid >> 3, j = tid & 7;
        int r = g * 1024 + u0 + j;
        biasS[tid] = bih[r] + bhh[r];
    }
    __syncthreads();

    const _Float16* wsp0 = &Ws[p15 * PAD + q * 8];          // packed cols 0..15
    const _Float16* wsp1 = &Ws[(16 + p15) * PAD + q * 8];   // packed cols 16..31
    const _Float16* wpp  = &Wp[p15 * PAD + q * 8];

    // ---- Phase B: XG table. Each wave: 64 classes (4 m-tiles of 16) ----
#pragma unroll
    for (int mt = 0; mt < 4; ++mt) {
        f32x4 a0 = {0.f,0.f,0.f,0.f}, a1 = {0.f,0.f,0.f,0.f};
        const float* ep = emb + (wave * 64 + mt * 16 + p15) * DM + q * 8;
#pragma unroll 8
        for (int ks = 0; ks < 32; ++ks) {
            h8v av = ld8f_cvt(ep + ks * 32);
            a0 = __builtin_amdgcn_mfma_f32_16x16x32_f16(
                av, *(const h8v*)(wsp0 + ks * 32), a0, 0, 0, 0);
            a1 = __builtin_amdgcn_mfma_f32_16x16x32_f16(
                av, *(const h8v*)(wsp1 + ks * 32), a1, 0, 0, 0);
        }
#pragma unroll
        for (int reg = 0; reg < 4; ++reg) {
            int row = wave * 64 + mt * 16 + q * 4 + reg;    // class index
            XGs[row * 32 + p15]      = (_Float16)(a0[reg] + biasS[p15]);
            XGs[row * 32 + 16 + p15] = (_Float16)(a1[reg] + biasS[16 + p15]);
        }
    }
    __syncthreads();

    // ---- Phase C: restage Ws with W_hh slice ----
    for (int idx = tid; idx < 32 * 128; idx += 512) {
        int c = idx >> 7, kc = idx & 127;
        int g = c >> 3, j = c & 7;
        *(h8v*)&Ws[c * PAD + kc * 8] =
            ld8f_cvt(&Whh[(g * 1024 + u0 + j) * DM + kc * 8]);
    }
    __syncthreads();

    const int wA = (b >> 5) * 2;                       // logits waves
    const bool isLog = (wave == wA) || (wave == wA + 1);
    const int  pw    = (wA + 2) & 7;                   // poll wave (never logits)
    const float bp_l = isLog ? bpred[C0 + p15] : 0.f;

    float csr[4] = {0.f, 0.f, 0.f, 0.f};               // cell state (fp32)

    // reader base offset into tiled h: element (k>>3)*1024 + row*8 (+k&7)
    const int hlane = q * 1024 + (wave * 16 + p15) * 8;

    // prefetched XG gate values for the upcoming step (x, XGs are static)
    f32x4 pA, pB;
#pragma unroll
    for (int reg = 0; reg < 4; ++reg) {
        int row = wave * 16 + q * 4 + reg;
        int cls = x[row];                               // step 0
        pA[reg] = (float)XGs[cls * 32 + p15];
        pB[reg] = (float)XGs[cls * 32 + 16 + p15];
    }

    // deferred logits store state (accL held across the barrier)
    f32x4 pendL;
    int   pendS = 0;
    bool  havePend = false;

#pragma unroll 1
    for (int p = 0; p <= SEQL; ++p) {
        const _Float16* hprevT = hbuf + (p % 3) * HELEMS;
        _Float16*       hnewT  = hbuf + ((p + 1) % 3) * HELEMS;
        const bool doGates = (p < SEQL);
        const bool doLogW  = (p >= 1) && isLog;

        // ---- flush deferred logits store (fire-and-forget; its HBM ack
        //      overlaps the gates compute and drains at the gates sync) ----
        if (havePend) {
#pragma unroll
            for (int reg = 0; reg < 4; ++reg) {
                int row = wave * 16 + q * 4 + reg;      // batch row
                __builtin_nontemporal_store(pendL[reg],
                    &out[row * (SEQL * NC) + pendS * NC + C0 + p15]);
            }
            havePend = false;
        }

        if (doGates) {
            f32x4 accA0 = pA, accB0 = pB;
            f32x4 accA1 = {0.f,0.f,0.f,0.f}, accB1 = {0.f,0.f,0.f,0.f};
            const _Float16* hb = hprevT + hlane;
#pragma unroll
            for (int kc = 0; kc < 4; ++kc) {
                h8v af[8];
#pragma unroll
                for (int jj = 0; jj < 8; ++jj)
                    af[jj] = *(const h8v*)(hb + (kc * 32 + jj * 4) * 1024);
                f32x4& aA = (kc < 2) ? accA0 : accA1;   // kc constant after unroll
                f32x4& aB = (kc < 2) ? accB0 : accB1;
#pragma unroll
                for (int jj = 0; jj < 8; ++jj) {
                    int ks = kc * 8 + jj;
                    aA = __builtin_amdgcn_mfma_f32_16x16x32_f16(
                        af[jj], *(const h8v*)(wsp0 + ks * 32), aA, 0, 0, 0);
                    aB = __builtin_amdgcn_mfma_f32_16x16x32_f16(
                        af[jj], *(const h8v*)(wsp1 + ks * 32), aB, 0, 0, 0);
                }
            }
            f32x4 accA = accA0 + accA1;
            f32x4 accB = accB0 + accB1;
            // cell update: lane p15<8 owns unit j=p15; lanes p15+8 hold f,o
#pragma unroll
            for (int reg = 0; reg < 4; ++reg) {
                float fv = __shfl_xor(accA[reg], 8, 64);
                float ov = __shfl_xor(accB[reg], 8, 64);
                if (p15 < 8) {
                    float iv = sigm(accA[reg]);
                    float ff = sigm(fv);
                    float gv = tanh_f(accB[reg]);
                    float oo = sigm(ov);
                    float c  = ff * csr[reg] + iv * gv;
                    csr[reg] = c;
                    int row = wave * 16 + q * 4 + reg;
                    // tiled block-private 2KB region; write-through to LLC
                    st_h_agent(&hnewT[b * 1024 + row * 8 + p15],
                               oo * tanh_f(c));
                }
            }
            __syncthreads();               // per-wave vmcnt(0): sc1 stores at LLC
            if (wave == pw && lane == 0)   // RELAXED arrival: no buffer_wbl2
                __hip_atomic_fetch_add(&cnt[(b & 7) * 32], 1u,
                                       __ATOMIC_RELAXED, __HIP_MEMORY_SCOPE_AGENT);

            // prefetch next step's XG gate values (static data; hides in window)
            if (p + 1 < SEQL) {
#pragma unroll
                for (int reg = 0; reg < 4; ++reg) {
                    int row = wave * 16 + q * 4 + reg;
                    int cls = x[(p + 1) * BATCH + row];
                    pA[reg] = (float)XGs[cls * 32 + p15];
                    pB[reg] = (float)XGs[cls * 32 + 16 + p15];
                }
            }
        }

        // ---- logits for timestep p-1, hidden under the barrier wait ----
        if (doLogW) {
            f32x4 accL = {0.f,0.f,0.f,0.f};
            const _Float16* hb = hprevT + hlane;
#pragma unroll 1
            for (int kc = 0; kc < 4; ++kc) {
                h8v af[8];
#pragma unroll
                for (int jj = 0; jj < 8; ++jj)
                    af[jj] = *(const h8v*)(hb + (kc * 32 + jj * 4) * 1024);
#pragma unroll
                for (int jj = 0; jj < 8; ++jj)
                    accL = __builtin_amdgcn_mfma_f32_16x16x32_f16(
                        af[jj], *(const h8v*)(wpp + (kc * 8 + jj) * 32), accL, 0, 0, 0);
            }
#pragma unroll
            for (int reg = 0; reg < 4; ++reg)
                pendL[reg] = accL[reg] + bp_l;
            pendS = p - 1;
            havePend = true;               // stored at next iteration top
        }

        if (doGates) {
            // ---- barrier exit: relaxed polls; ONE acquire inv per step ----
            if (wave == pw && lane < 8) {
                const unsigned target = (unsigned)(p + 1) * 16u;
                while (__hip_atomic_load(&cnt[lane * 32], __ATOMIC_RELAXED,
                                         __HIP_MEMORY_SCOPE_AGENT) < target)
                    __builtin_amdgcn_s_sleep(1);
                // buffer_inv sc1: drops clean lines only (dirty out survives)
                __builtin_amdgcn_fence(__ATOMIC_ACQUIRE, "agent");
            }
            __syncthreads();
        }
    }

    // ---- final deferred logits store (s = SEQL-1) ----
    if (havePend) {
#pragma unroll
        for (int reg = 0; reg < 4; ++reg) {
            int row = wave * 16 + q * 4 + reg;
            __builtin_nontemporal_store(pendL[reg],
                &out[row * (SEQL * NC) + pendS * NC + C0 + p15]);
        }
    }
}

// ---------------------------------------------------------------------------
extern "C" void kernel_launch(void* const* d_in, const int* in_sizes, int n_in,
                              void* d_out, int out_size, void* d_ws, size_t ws_size,
                              hipStream_t stream) {
    (void)in_sizes; (void)n_in; (void)out_size; (void)ws_size;
    const int*   x     = (const int*)  d_in[0];
    const float* emb   = (const float*)d_in[1];
    const float* Wih   = (const float*)d_in[2];
    const float* Whh   = (const float*)d_in[3];
    const float* bih   = (const float*)d_in[4];
    const float* bhh   = (const float*)d_in[5];
    const float* Wpred = (const float*)d_in[6];
    const float* bpred = (const float*)d_in[7];
    float* out = (float*)d_out;

    unsigned*  cnt  = (unsigned*)d_ws;                   // 8 counters, 128B apart
    _Float16*  hbuf = (_Float16*)((char*)d_ws + 1024);   // 3 x 128x1024 fp16 ring

    // zero counters + h ring buffer 0 (buffers 1,2 are fully written before read)
    hipMemsetAsync(d_ws, 0, 1024 + HELEMS * 2, stream);

    hipLaunchKernelGGL(lstm_all_kernel, dim3(128), dim3(512), 0, stream,
                       x, emb, Wih, Whh, bih, bhh, Wpred, bpred,
                       hbuf, cnt, out);
}

// Round 5
// 5810.271 us; speedup vs baseline: 1.6788x; 1.6094x over previous
//
#include <hip/hip_runtime.h>

// ---------------------------------------------------------------------------
// SequencePredictorRNN: LSTM(1024 steps, batch 128, d=1024) + 512-class readout
//
// Persistent kernel, 128 blocks x 512 threads. Block b owns hidden units
// [8b,8b+8) -> 32 packed gate columns in LDS; XG input-gate table (512 classes)
// in LDS. Logits MFMA hidden under the barrier wait (3-deep h ring).
//
// R5 = R2 structure (8.45ms; R3's K-split and R4's deferred stores both
// regressed and are reverted) + fence elimination:
//  * The per-step agent-acquire fence (buffer_inv sc1) was 16 L2-wipes per
//    XCD per step, landing inside co-resident blocks' h-pull windows ->
//    all h traffic repeatedly re-served from LLC, plus read-only data (x)
//    endlessly refetched from HBM (FETCH_SIZE 1.08GB ~ 1MB/step).
//  * Now h loads are LLC-direct (inline asm global_load_dwordx4 sc0 sc1,
//    bypassing L1+L2) and the fence is REMOVED. Coherence chain:
//    producer sc1 stores ack at LLC (vmcnt0 at syncthreads) < relaxed
//    arrival RMW at LLC < consumer poll observes RMW < consumer LLC-direct
//    loads. No cache can serve stale h; nothing else is cross-step shared.
//  * Rule-18 discipline: fragment regs tied "+v" through the s_waitcnt asm
//    so MFMAs can't hoist above it; sched_barrier(0) after.
//  * L1/L2 stay permanently warm for x/XG prefetch (never invalidated).
//  * Poll + arrival RMW on the non-logits wave pw (R4's one good piece).
//  * __launch_bounds__(512,2): VGPR headroom for af[16]+voff[32].
// Workspace: 1KB counters + 3 x 128x1024 fp16 h buffers = 769 KB.
// ---------------------------------------------------------------------------

typedef _Float16 h8v  __attribute__((ext_vector_type(8)));   // 8 x fp16 (4 VGPR)
typedef float    f32x4 __attribute__((ext_vector_type(4)));

#define SEQL  1024
#define BATCH 128
#define DM    1024
#define NC    512
#define PAD   1032
#define HELEMS (BATCH * DM)    // fp16 elems per h buffer (256 KB)

__device__ __forceinline__ float sigm(float x)   { return 1.0f / (1.0f + __expf(-x)); }
__device__ __forceinline__ float tanh_f(float x) { return 1.0f - 2.0f / (__expf(2.0f * x) + 1.0f); }

__device__ __forceinline__ h8v ld8f_cvt(const float* p) {
    const float4 a = ((const float4*)p)[0];
    const float4 b = ((const float4*)p)[1];
    h8v v;
    v[0] = (_Float16)a.x; v[1] = (_Float16)a.y;
    v[2] = (_Float16)a.z; v[3] = (_Float16)a.w;
    v[4] = (_Float16)b.x; v[5] = (_Float16)b.y;
    v[6] = (_Float16)b.z; v[7] = (_Float16)b.w;
    return v;
}

// agent-scope write-through fp16 store (global_store_short sc0 sc1, tracked)
__device__ __forceinline__ void st_h_agent(_Float16* p, float v) {
    _Float16 hv = (_Float16)v;
    unsigned short u = __builtin_bit_cast(unsigned short, hv);
    __hip_atomic_store((unsigned short*)p, u, __ATOMIC_RELAXED,
                       __HIP_MEMORY_SCOPE_AGENT);
}

// LLC-direct 16B load: bypasses L1 (sc0) and L2 (sc1) -> coherence point.
#define LDH_LLC(dst, vo, base)                                          \
    asm volatile("global_load_dwordx4 %0, %1, %2 sc0 sc1"               \
                 : "=v"(dst) : "v"(vo), "s"(base))

// wait for all loads; ties fragment regs so MFMAs can't hoist above (rule 18)
#define WAIT_TIE16(a)                                                   \
    asm volatile("s_waitcnt vmcnt(0)"                                   \
        : "+v"(a[0]),"+v"(a[1]),"+v"(a[2]),"+v"(a[3]),                  \
          "+v"(a[4]),"+v"(a[5]),"+v"(a[6]),"+v"(a[7]),                  \
          "+v"(a[8]),"+v"(a[9]),"+v"(a[10]),"+v"(a[11]),                \
          "+v"(a[12]),"+v"(a[13]),"+v"(a[14]),"+v"(a[15]));             \
    __builtin_amdgcn_sched_barrier(0)

__global__ __launch_bounds__(512, 2) void lstm_all_kernel(
    const int*   __restrict__ x,     const float* __restrict__ emb,
    const float* __restrict__ Wih,   const float* __restrict__ Whh,
    const float* __restrict__ bih,   const float* __restrict__ bhh,
    const float* __restrict__ Wpred, const float* __restrict__ bpred,
    _Float16* __restrict__ hbuf, unsigned* __restrict__ cnt,
    float* __restrict__ out)
{
    __shared__ __align__(16) _Float16 Ws[32 * PAD];  // W_ih slice, then W_hh
    __shared__ __align__(16) _Float16 Wp[16 * PAD];  // W_pred slice (16 x 1024)
    __shared__ _Float16 XGs[512 * 32];               // XG table: class x 32 cols
    __shared__ float biasS[32];

    const int tid  = threadIdx.x;
    const int b    = blockIdx.x;
    const int u0   = b * 8;                 // first hidden unit owned
    const int C0   = (b & 31) * 16;         // logits column base
    const int wave = tid >> 6, lane = tid & 63;
    const int q = lane >> 4, p15 = lane & 15;

    // ---- Phase A: stage W_ih slice, W_pred slice, biases ----
    for (int idx = tid; idx < 32 * 128; idx += 512) {
        int c = idx >> 7, kc = idx & 127;
        int g = c >> 3, j = c & 7;
        *(h8v*)&Ws[c * PAD + kc * 8] =
            ld8f_cvt(&Wih[(g * 1024 + u0 + j) * DM + kc * 8]);
    }
    for (int idx = tid; idx < 16 * 128; idx += 512) {
        int rr = idx >> 7, kc = idx & 127;
        *(h8v*)&Wp[rr * PAD + kc * 8] =
            ld8f_cvt(&Wpred[(C0 + rr) * DM + kc * 8]);
    }
    if (tid < 32) {
        int g = tid >> 3, j = tid & 7;
        int r = g * 1024 + u0 + j;
        biasS[tid] = bih[r] + bhh[r];
    }
    __syncthreads();

    const _Float16* wsp0 = &Ws[p15 * PAD + q * 8];          // packed cols 0..15
    const _Float16* wsp1 = &Ws[(16 + p15) * PAD + q * 8];   // packed cols 16..31
    const _Float16* wpp  = &Wp[p15 * PAD + q * 8];

    // ---- Phase B: XG table. Each wave: 64 classes (4 m-tiles of 16) ----
#pragma unroll
    for (int mt = 0; mt < 4; ++mt) {
        f32x4 a0 = {0.f,0.f,0.f,0.f}, a1 = {0.f,0.f,0.f,0.f};
        const float* ep = emb + (wave * 64 + mt * 16 + p15) * DM + q * 8;
#pragma unroll 8
        for (int ks = 0; ks < 32; ++ks) {
            h8v av = ld8f_cvt(ep + ks * 32);
            a0 = __builtin_amdgcn_mfma_f32_16x16x32_f16(
                av, *(const h8v*)(wsp0 + ks * 32), a0, 0, 0, 0);
            a1 = __builtin_amdgcn_mfma_f32_16x16x32_f16(
                av, *(const h8v*)(wsp1 + ks * 32), a1, 0, 0, 0);
        }
#pragma unroll
        for (int reg = 0; reg < 4; ++reg) {
            int row = wave * 64 + mt * 16 + q * 4 + reg;    // class index
            XGs[row * 32 + p15]      = (_Float16)(a0[reg] + biasS[p15]);
            XGs[row * 32 + 16 + p15] = (_Float16)(a1[reg] + biasS[16 + p15]);
        }
    }
    __syncthreads();

    // ---- Phase C: restage Ws with W_hh slice ----
    for (int idx = tid; idx < 32 * 128; idx += 512) {
        int c = idx >> 7, kc = idx & 127;
        int g = c >> 3, j = c & 7;
        *(h8v*)&Ws[c * PAD + kc * 8] =
            ld8f_cvt(&Whh[(g * 1024 + u0 + j) * DM + kc * 8]);
    }
    __syncthreads();

    const int wA = (b >> 5) * 2;                       // logits waves
    const bool isLog = (wave == wA) || (wave == wA + 1);
    const int  pw    = (wA + 2) & 7;                   // poll wave (never logits)
    const float bp_l = isLog ? bpred[C0 + p15] : 0.f;

    float csr[4] = {0.f, 0.f, 0.f, 0.f};               // cell state (fp32)

    // reader base offset into tiled h: element (k>>3)*1024 + row*8 (+k&7)
    const int hlane = q * 1024 + (wave * 16 + p15) * 8;

    // loop-invariant byte voffsets for the 32 h fragments (gates & logits)
    unsigned voff[32];
#pragma unroll
    for (int i = 0; i < 32; ++i)
        voff[i] = (unsigned)((hlane + ((i >> 3) * 32 + (i & 7) * 4) * 1024) * 2);

    // prefetched XG gate values for the upcoming step (x, XGs are static)
    f32x4 pA, pB;
#pragma unroll
    for (int reg = 0; reg < 4; ++reg) {
        int row = wave * 16 + q * 4 + reg;
        int cls = x[row];                               // step 0
        pA[reg] = (float)XGs[cls * 32 + p15];
        pB[reg] = (float)XGs[cls * 32 + 16 + p15];
    }

#pragma unroll 1
    for (int p = 0; p <= SEQL; ++p) {
        const _Float16* hprevT = hbuf + (p % 3) * HELEMS;
        _Float16*       hnewT  = hbuf + ((p + 1) % 3) * HELEMS;
        const bool doGates = (p < SEQL);
        const bool doLogW  = (p >= 1) && isLog;

        if (doGates) {
            f32x4 accA = pA, accB = pB;
            h8v af[16];
            // ---- batch 0: fragments 0..15 (LLC-direct) ----
#pragma unroll
            for (int i = 0; i < 16; ++i) LDH_LLC(af[i], voff[i], hprevT);
            WAIT_TIE16(af);
#pragma unroll
            for (int i = 0; i < 16; ++i) {
                accA = __builtin_amdgcn_mfma_f32_16x16x32_f16(
                    af[i], *(const h8v*)(wsp0 + i * 32), accA, 0, 0, 0);
                accB = __builtin_amdgcn_mfma_f32_16x16x32_f16(
                    af[i], *(const h8v*)(wsp1 + i * 32), accB, 0, 0, 0);
            }
            // ---- batch 1: fragments 16..31 ----
#pragma unroll
            for (int i = 0; i < 16; ++i) LDH_LLC(af[i], voff[16 + i], hprevT);
            WAIT_TIE16(af);
#pragma unroll
            for (int i = 0; i < 16; ++i) {
                accA = __builtin_amdgcn_mfma_f32_16x16x32_f16(
                    af[i], *(const h8v*)(wsp0 + (16 + i) * 32), accA, 0, 0, 0);
                accB = __builtin_amdgcn_mfma_f32_16x16x32_f16(
                    af[i], *(const h8v*)(wsp1 + (16 + i) * 32), accB, 0, 0, 0);
            }
            // cell update: lane p15<8 owns unit j=p15; lanes p15+8 hold f,o
#pragma unroll
            for (int reg = 0; reg < 4; ++reg) {
                float fv = __shfl_xor(accA[reg], 8, 64);
                float ov = __shfl_xor(accB[reg], 8, 64);
                if (p15 < 8) {
                    float iv = sigm(accA[reg]);
                    float ff = sigm(fv);
                    float gv = tanh_f(accB[reg]);
                    float oo = sigm(ov);
                    float c  = ff * csr[reg] + iv * gv;
                    csr[reg] = c;
                    int row = wave * 16 + q * 4 + reg;
                    // tiled block-private 2KB region; write-through to LLC
                    st_h_agent(&hnewT[b * 1024 + row * 8 + p15],
                               oo * tanh_f(c));
                }
            }
            __syncthreads();               // per-wave vmcnt(0): sc1 stores at LLC
            if (wave == pw && lane == 0)   // RELAXED arrival: no buffer_wbl2
                __hip_atomic_fetch_add(&cnt[(b & 7) * 32], 1u,
                                       __ATOMIC_RELAXED, __HIP_MEMORY_SCOPE_AGENT);

            // prefetch next step's XG gate values (L2 stays warm: no invs)
            if (p + 1 < SEQL) {
#pragma unroll
                for (int reg = 0; reg < 4; ++reg) {
                    int row = wave * 16 + q * 4 + reg;
                    int cls = x[(p + 1) * BATCH + row];
                    pA[reg] = (float)XGs[cls * 32 + p15];
                    pB[reg] = (float)XGs[cls * 32 + 16 + p15];
                }
            }
        }

        // ---- logits for timestep p-1, hidden under the barrier wait ----
        if (doLogW) {
            f32x4 accL = {0.f,0.f,0.f,0.f};
            h8v af[16];
#pragma unroll
            for (int i = 0; i < 16; ++i) LDH_LLC(af[i], voff[i], hprevT);
            WAIT_TIE16(af);
#pragma unroll
            for (int i = 0; i < 16; ++i)
                accL = __builtin_amdgcn_mfma_f32_16x16x32_f16(
                    af[i], *(const h8v*)(wpp + i * 32), accL, 0, 0, 0);
#pragma unroll
            for (int i = 0; i < 16; ++i) LDH_LLC(af[i], voff[16 + i], hprevT);
            WAIT_TIE16(af);
#pragma unroll
            for (int i = 0; i < 16; ++i)
                accL = __builtin_amdgcn_mfma_f32_16x16x32_f16(
                    af[i], *(const h8v*)(wpp + (16 + i) * 32), accL, 0, 0, 0);
            const int s = p - 1;
#pragma unroll
            for (int reg = 0; reg < 4; ++reg) {
                int row = wave * 16 + q * 4 + reg;      // batch row
                __builtin_nontemporal_store(accL[reg] + bp_l,
                    &out[row * (SEQL * NC) + s * NC + C0 + p15]);
            }
        }

        if (doGates) {
            // ---- barrier exit: relaxed polls; NO fence (h is LLC-direct) ----
            if (wave == pw && lane < 8) {
                const unsigned target = (unsigned)(p + 1) * 16u;
                while (__hip_atomic_load(&cnt[lane * 32], __ATOMIC_RELAXED,
                                         __HIP_MEMORY_SCOPE_AGENT) < target)
                    __builtin_amdgcn_s_sleep(1);
            }
            __syncthreads();
        }
    }
}

// ---------------------------------------------------------------------------
extern "C" void kernel_launch(void* const* d_in, const int* in_sizes, int n_in,
                              void* d_out, int out_size, void* d_ws, size_t ws_size,
                              hipStream_t stream) {
    (void)in_sizes; (void)n_in; (void)out_size; (void)ws_size;
    const int*   x     = (const int*)  d_in[0];
    const float* emb   = (const float*)d_in[1];
    const float* Wih   = (const float*)d_in[2];
    const float* Whh   = (const float*)d_in[3];
    const float* bih   = (const float*)d_in[4];
    const float* bhh   = (const float*)d_in[5];
    const float* Wpred = (const float*)d_in[6];
    const float* bpred = (const float*)d_in[7];
    float* out = (float*)d_out;

    unsigned*  cnt  = (unsigned*)d_ws;                   // 8 counters, 128B apart
    _Float16*  hbuf = (_Float16*)((char*)d_ws + 1024);   // 3 x 128x1024 fp16 ring

    // zero counters + h ring buffer 0 (buffers 1,2 are fully written before read)
    hipMemsetAsync(d_ws, 0, 1024 + HELEMS * 2, stream);

    hipLaunchKernelGGL(lstm_all_kernel, dim3(128), dim3(512), 0, stream,
                       x, emb, Wih, Whh, bih, bhh, Wpred, bpred,
                       hbuf, cnt, out);
}